// Round 1
// baseline (59.628 us; speedup 1.0000x reference)
//
#include <hip/hip_runtime.h>

// BilinearSampler: image (B,H,W,C) f32, grid (B,H,W,2) f32 -> out (B,H,W,C) f32
// B=16, H=256, W=256, C=32.
// Mapping: 8 threads per output pixel, each thread handles 4 channels (float4).
// Channels are innermost+contiguous, so each neighbor gather is a coalesced
// 128B segment across the 8-lane group.

constexpr int Bn = 16, Hn = 256, Wn = 256, Cn = 32;

__global__ __launch_bounds__(256) void BilinearSampler_29300266893747_kernel(
    const float* __restrict__ image,
    const float* __restrict__ grid,
    float* __restrict__ out)
{
    const long long t = (long long)blockIdx.x * blockDim.x + threadIdx.x;
    const long long total = (long long)Bn * Hn * Wn * 8;  // 8 threads/pixel
    if (t >= total) return;

    const int q = (int)(t & 7);          // channel quad index: channels q*4..q*4+3
    const long long p = t >> 3;          // pixel index in [0, B*H*W)
    const int b = (int)(p >> 16);        // H*W = 65536

    // grid coords (float2 per pixel; 8 lanes of the same pixel broadcast)
    const float2 g = ((const float2*)grid)[p];

    // match reference rounding order: ((g + 1) * (W-1)) / 2
    const float x = (g.x + 1.0f) * 255.0f * 0.5f;
    const float y = (g.y + 1.0f) * 255.0f * 0.5f;

    const float xf = floorf(x);
    const float yf = floorf(y);
    const int x0 = (int)xf;
    const int y0 = (int)yf;
    const int x1 = x0 + 1;
    const int y1 = y0 + 1;

    const int x0c = min(max(x0, 0), Wn - 1);
    const int x1c = min(max(x1, 0), Wn - 1);
    const int y0c = min(max(y0, 0), Hn - 1);
    const int y1c = min(max(y1, 0), Hn - 1);

    const float x0f = (float)x0c, x1f = (float)x1c;
    const float y0f = (float)y0c, y1f = (float)y1c;

    const float wa = (x1f - x) * (y1f - y);
    const float wb = (x1f - x) * (y - y0f);
    const float wc = (x - x0f) * (y1f - y);
    const float wd = (x - x0f) * (y - y0f);

    const float* img_b = image + (long long)b * Hn * Wn * Cn;
    const int co = q * 4;

    const float4 Ia = *(const float4*)(img_b + ((long long)y0c * Wn + x0c) * Cn + co);
    const float4 Ib = *(const float4*)(img_b + ((long long)y1c * Wn + x0c) * Cn + co);
    const float4 Ic = *(const float4*)(img_b + ((long long)y0c * Wn + x1c) * Cn + co);
    const float4 Id = *(const float4*)(img_b + ((long long)y1c * Wn + x1c) * Cn + co);

    float4 o;
    o.x = wa * Ia.x + wb * Ib.x + wc * Ic.x + wd * Id.x;
    o.y = wa * Ia.y + wb * Ib.y + wc * Ic.y + wd * Id.y;
    o.z = wa * Ia.z + wb * Ib.z + wc * Ic.z + wd * Id.z;
    o.w = wa * Ia.w + wb * Ib.w + wc * Ic.w + wd * Id.w;

    *(float4*)(out + p * Cn + co) = o;
}

extern "C" void kernel_launch(void* const* d_in, const int* in_sizes, int n_in,
                              void* d_out, int out_size, void* d_ws, size_t ws_size,
                              hipStream_t stream) {
    const float* image = (const float*)d_in[0];
    const float* grid  = (const float*)d_in[1];
    float* out = (float*)d_out;

    const long long total = (long long)Bn * Hn * Wn * 8;  // 8,388,608 threads
    const int block = 256;
    const int nblocks = (int)((total + block - 1) / block);  // 32768

    BilinearSampler_29300266893747_kernel<<<nblocks, block, 0, stream>>>(image, grid, out);
}